// Round 5
// baseline (502.354 us; speedup 1.0000x reference)
//
#include <hip/hip_runtime.h>
#include <cstdint>
#include <cstddef>

typedef unsigned short u16;
typedef unsigned int   u32;
using short8 = __attribute__((ext_vector_type(8))) short;
using f32x4  = __attribute__((ext_vector_type(4))) float;

// B=8, N=8192, H=256, A=64 (F=320), S=32
#define NB    8
#define NN    8192
#define HH    256
#define FF    320
#define SS    32
#define NROWS 65536
#define NCH   64            // pooling K-split chunks (128 n each)

__device__ __forceinline__ u16 f2bf(float f) {          // exact RNE (prep only)
    union { float f; u32 u; } v; v.f = f;
    u32 r = v.u + 0x7fffu + ((v.u >> 16) & 1u);
    return (u16)(r >> 16);
}
// round-half-up bf16 pack: (hi.bf16 << 16) | lo.bf16 in 3 VALU ops
__device__ __forceinline__ u32 pk2h(float lo, float hi) {
    union { float f; u32 u; } a, b; a.f = lo; b.f = hi;
    return __builtin_amdgcn_perm(b.u + 0x8000u, a.u + 0x8000u, 0x07060302u);
}
__device__ __forceinline__ short8 pack8(float4 a, float4 b) {
    union { u32 u[4]; short8 s; } r;
    r.u[0] = pk2h(a.x, a.y); r.u[1] = pk2h(a.z, a.w);
    r.u[2] = pk2h(b.x, b.y); r.u[3] = pk2h(b.z, b.w);
    return r.s;
}

// ---------------- prep: cast Wi,Wj to bf16 (concat, exact RNE) ----------------
__global__ __launch_bounds__(256) void prep_w(const float* __restrict__ Wi,
                                              const float* __restrict__ Wj,
                                              u16* __restrict__ Wb) {
    int idx = blockIdx.x * 256 + threadIdx.x;       // 0..163839
    float v = (idx < 81920) ? Wi[idx] : Wj[idx - 81920];
    Wb[idx] = f2bf(v);
}

// ---------------- kernel 1: gated features + norm^2 partials ----------------
// 512 thr (8 waves), 512 rows x 128 cols (2 mats x 64 h); wave = 64 rows (4 mt).
// B full-K LDS-resident (80 KB, one barrier); A direct global->VGPR, ring-3 prefetch.
// Grid 512 = exactly 2 blocks/CU resident, one round. normsq written per-ht (no atomics).
__global__ __launch_bounds__(512, 4) void gemm_gate(
    const float* __restrict__ x, const u16* __restrict__ Wb,
    const float* __restrict__ bi, const float* __restrict__ bj,
    u16* __restrict__ xa, float* __restrict__ normsq_p)
{
    __shared__ u16 lB[5 * 8192];      // [kt][row 0..127][swizzled k-slot*8], 81920 B

    const int bx   = blockIdx.x;
    const int xcd  = bx & 7;
    const int ht   = (bx >> 3) & 3;
    const int slot = bx >> 5;         // 0..15
    const int mb   = xcd + slot * 8;  // 0..127
    const int m0   = mb * 512;
    const int h0   = ht * 64;
    const int b_idx = m0 >> 13;
    const int n0    = m0 & 8191;

    const int tid  = threadIdx.x;
    const int w    = tid >> 6;        // 0..7
    const int lane = tid & 63;
    const int quad = lane >> 4;
    const int l15  = lane & 15;

    // ---- one-time B load: 5 kt x 2 issues per wave ----
    {
        const int rsub = lane >> 3;                 // 0..7
        const int kg   = (lane & 7) ^ rsub;         // XOR swizzle
        #pragma unroll
        for (int kt = 0; kt < 5; ++kt) {
            #pragma unroll
            for (int j = 0; j < 2; ++j) {
                int sl  = w * 2 + j;                // 0..15
                int row = sl * 8 + rsub;            // 0..127
                int mat = row >> 6, hl = row & 63;
                const u16* gsrc = Wb + mat * 81920 + (size_t)(h0 + hl) * FF + kt * 64 + kg * 8;
                u16* ldst = &lB[kt * 8192 + sl * 512];
                __builtin_amdgcn_global_load_lds(
                    (const __attribute__((address_space(1))) void*)gsrc,
                    (__attribute__((address_space(3))) void*)ldst, 16, 0, 0);
            }
        }
    }

    // ---- A fragment addressing: row = m0 + w*64 + mt*16 + l15, k = ks*32 + quad*8 ----
    const float* xb = x + (size_t)(m0 + w * 64 + l15) * FF + quad * 8;

    f32x4 acc[8][4];                  // [col/16][mt]
    #pragma unroll
    for (int a = 0; a < 8; ++a)
        #pragma unroll
        for (int m = 0; m < 4; ++m) acc[a][m] = (f32x4){0.f, 0.f, 0.f, 0.f};

    float4 pre[3][4][2];              // [ring][mt][half] — distance-2 prefetch
    #pragma unroll
    for (int s = 0; s < 2; ++s)
        #pragma unroll
        for (int mt = 0; mt < 4; ++mt) {
            pre[s][mt][0] = *reinterpret_cast<const float4*>(xb + mt * 16 * FF + s * 32);
            pre[s][mt][1] = *reinterpret_cast<const float4*>(xb + mt * 16 * FF + s * 32 + 4);
        }

    __syncthreads();                  // B resident

    #pragma unroll
    for (int ks = 0; ks < 10; ++ks) {
        const int kt  = ks >> 1, kk = ks & 1;
        const int cur = ks % 3;
        if (ks < 8) {
            const int nx = (ks + 2) % 3;
            const int f  = (ks + 2) * 32;
            #pragma unroll
            for (int mt = 0; mt < 4; ++mt) {
                pre[nx][mt][0] = *reinterpret_cast<const float4*>(xb + mt * 16 * FF + f);
                pre[nx][mt][1] = *reinterpret_cast<const float4*>(xb + mt * 16 * FF + f + 4);
            }
        }
        short8 af[4];
        #pragma unroll
        for (int mt = 0; mt < 4; ++mt)
            af[mt] = pack8(pre[cur][mt][0], pre[cur][mt][1]);
        #pragma unroll
        for (int mn = 0; mn < 8; ++mn) {
            int c = mn * 16 + l15;
            short8 bv = *reinterpret_cast<const short8*>(
                &lB[kt * 8192 + c * 64 + (((kk * 4 + quad) ^ (c & 7)) << 3)]);
            #pragma unroll
            for (int mt = 0; mt < 4; ++mt)
                acc[mn][mt] = __builtin_amdgcn_mfma_f32_16x16x32_bf16(af[mt], bv, acc[mn][mt], 0, 0, 0);
        }
    }

    // ---- epilogue: gate, store xa [b][h][n], norm^2 partials ----
    float s0[4][4];
    #pragma unroll
    for (int mt = 0; mt < 4; ++mt)
        #pragma unroll
        for (int r = 0; r < 4; ++r) s0[mt][r] = 0.f;

    #pragma unroll
    for (int hq = 0; hq < 4; ++hq) {
        int h = h0 + hq * 16 + l15;
        float bi_v = bi[h], bj_v = bj[h];
        #pragma unroll
        for (int mt = 0; mt < 4; ++mt) {
            float xall[4];
            #pragma unroll
            for (int r = 0; r < 4; ++r) {
                float yi = acc[hq][mt][r] + bi_v;
                float yj = acc[hq + 4][mt][r] + bj_v;
                float sg = 1.f / (1.f + __expf(-yi));
                float e2 = __expf(-2.f * yj);
                float th = (1.f - e2) / (1.f + e2);
                float xv = sg * th;
                xall[r] = xv;
                s0[mt][r] += xv * xv;
            }
            uint2 pk;
            pk.x = pk2h(xall[0], xall[1]);
            pk.y = pk2h(xall[2], xall[3]);
            size_t o = (size_t)b_idx * ((size_t)HH * NN) + (size_t)h * NN
                     + (size_t)(n0 + w * 64 + mt * 16 + quad * 4);
            *reinterpret_cast<uint2*>(&xa[o]) = pk;
        }
    }
    #pragma unroll
    for (int m = 1; m <= 8; m <<= 1) {
        #pragma unroll
        for (int mt = 0; mt < 4; ++mt)
            #pragma unroll
            for (int r = 0; r < 4; ++r)
                s0[mt][r] += __shfl_xor(s0[mt][r], m, 64);
    }
    if (l15 == 0) {
        #pragma unroll
        for (int mt = 0; mt < 4; ++mt)
            #pragma unroll
            for (int r = 0; r < 4; ++r)
                normsq_p[ht * NROWS + m0 + w * 64 + mt * 16 + quad * 4 + r] = s0[mt][r];
    }
}

// ---------------- kernel 2: masked softmax over N per (b,s) -> out1 fp32 ----------------
__global__ __launch_bounds__(1024) void softmax_k(
    const float* __restrict__ nm, const float* __restrict__ normsq_p,
    float* __restrict__ out1)
{
    __shared__ float red[16];
    int bs = blockIdx.x;                 // 0..255
    int b  = bs >> 5;
    const float* src = nm + (size_t)bs * NN;
    float* dst       = out1 + (size_t)bs * NN;
    const float* ns  = normsq_p + (size_t)b * NN;
    int tid = threadIdx.x;
    float e[8];
    float sum = 0.f;
    #pragma unroll
    for (int i = 0; i < 8; ++i) {
        int n = i * 1024 + tid;
        float nsq = ns[n] + ns[n + NROWS] + ns[n + 2 * NROWS] + ns[n + 3 * NROWS];
        float logit = src[n] * sqrtf(nsq);
        float v = (logit > 0.f) ? __expf(logit) : 0.f;
        e[i] = v;
        sum += v;
    }
    #pragma unroll
    for (int m = 1; m <= 32; m <<= 1) sum += __shfl_xor(sum, m, 64);
    int w = tid >> 6, lane = tid & 63;
    if (lane == 0) red[w] = sum;
    __syncthreads();
    float part = 0.f;
    #pragma unroll
    for (int j = 0; j < 16; ++j) part += red[j];
    float inv = (part > 0.f) ? (1.f / part) : 0.f;
    #pragma unroll
    for (int i = 0; i < 8; ++i) dst[i * 1024 + tid] = e[i] * inv;
}

// ---------------- kernel 3: pooling GEMM partials over 128-n chunks ----------------
__global__ __launch_bounds__(256) void pooled_k(
    const u16* __restrict__ xa, const float* __restrict__ wgt,
    float* __restrict__ part)
{
    __shared__ u16 lw[32 * 136];         // [s][k] stride 136 shorts
    int bx = blockIdx.x;                 // 512
    int b  = bx >> 6, c = bx & 63;
    int n0 = c * 128;
    int tid = threadIdx.x, w = tid >> 6, lane = tid & 63, quad = lane >> 4, l15 = lane & 15;

    const u16* ab = xa + (size_t)b * ((size_t)HH * NN) + n0;

    // prefetch ks=0 A-fragments before the barrier (independent of LDS)
    short8 av[2][4];
    #pragma unroll
    for (int htl = 0; htl < 4; ++htl) {
        int h = w * 64 + htl * 16 + l15;
        av[0][htl] = *reinterpret_cast<const short8*>(ab + (size_t)h * NN + quad * 8);
    }

    // stage weights fp32 -> bf16 (32 s x 128 n)
    {
        int s  = tid >> 3;
        int jq = (tid & 7) * 16;
        const float* src = wgt + (size_t)(b * SS + s) * NN + n0 + jq;
        #pragma unroll
        for (int q = 0; q < 4; ++q) {
            float4 v = *reinterpret_cast<const float4*>(src + q * 4);
            uint2 pk;
            pk.x = pk2h(v.x, v.y);
            pk.y = pk2h(v.z, v.w);
            *reinterpret_cast<uint2*>(&lw[s * 136 + jq + q * 4]) = pk;
        }
    }
    __syncthreads();

    f32x4 acc[4][2];
    #pragma unroll
    for (int a = 0; a < 4; ++a)
        #pragma unroll
        for (int s = 0; s < 2; ++s) acc[a][s] = (f32x4){0.f, 0.f, 0.f, 0.f};

    #pragma unroll
    for (int ks = 0; ks < 4; ++ks) {
        const int cur = ks & 1, nxt = cur ^ 1;
        if (ks < 3) {
            #pragma unroll
            for (int htl = 0; htl < 4; ++htl) {
                int h = w * 64 + htl * 16 + l15;
                av[nxt][htl] = *reinterpret_cast<const short8*>(
                    ab + (size_t)h * NN + (ks + 1) * 32 + quad * 8);
            }
        }
        #pragma unroll
        for (int st = 0; st < 2; ++st) {
            int s = st * 16 + l15;
            short8 bv = *reinterpret_cast<const short8*>(&lw[s * 136 + ks * 32 + quad * 8]);
            #pragma unroll
            for (int htl = 0; htl < 4; ++htl)
                acc[htl][st] = __builtin_amdgcn_mfma_f32_16x16x32_bf16(av[cur][htl], bv, acc[htl][st], 0, 0, 0);
        }
    }
    float* pb = part + (size_t)(b * NCH + c) * 8192;   // [s*256 + h]
    #pragma unroll
    for (int htl = 0; htl < 4; ++htl) {
        #pragma unroll
        for (int st = 0; st < 2; ++st) {
            int h = w * 64 + htl * 16 + quad * 4;
            int s = st * 16 + l15;
            *reinterpret_cast<f32x4*>(&pb[s * 256 + h]) = acc[htl][st];
        }
    }
}

// ---------------- kernel 4: reduce partials over 64 chunks + tanh -> out0 ----------------
__global__ __launch_bounds__(256) void reduce_tanh(const float* __restrict__ part,
                                                   float* __restrict__ out0)
{
    int gid = blockIdx.x * 256 + threadIdx.x;   // 0..65535 = b*8192 + s*256 + h
    int b = gid >> 13, r = gid & 8191;
    const float* p = part + (size_t)b * NCH * 8192 + r;
    float s = 0.f;
    #pragma unroll
    for (int c = 0; c < NCH; ++c) s += p[(size_t)c * 8192];
    out0[gid] = tanhf(s);
}

extern "C" void kernel_launch(void* const* d_in, const int* in_sizes, int n_in,
                              void* d_out, int out_size, void* d_ws, size_t ws_size,
                              hipStream_t stream) {
    const float* x  = (const float*)d_in[0];
    const float* nm = (const float*)d_in[1];
    const float* Wi = (const float*)d_in[2];
    const float* bi = (const float*)d_in[3];
    const float* Wj = (const float*)d_in[4];
    const float* bj = (const float*)d_in[5];
    float* out0 = (float*)d_out;
    float* out1 = out0 + NB * SS * HH;           // 65536

    char* ws = (char*)d_ws;
    u16*   Wb       = (u16*)ws;                            // 327,680 B
    u16*   xa       = (u16*)(ws + 327680);                 // 33,554,432 B
    float* part     = (float*)(ws + 327680 + 33554432);    // 16,777,216 B
    // normsq partials alias the head of part: written by gemm, read by softmax,
    // then pooled_k overwrites (stream-ordered, safe). [4][65536] f32 = 1 MB.
    float* normsq_p = part;

    prep_w     <<<640,  256, 0, stream>>>(Wi, Wj, Wb);
    gemm_gate  <<<512,  512, 0, stream>>>(x, Wb, bi, bj, xa, normsq_p);
    softmax_k  <<<256, 1024, 0, stream>>>(nm, normsq_p, out1);
    pooled_k   <<<512,  256, 0, stream>>>(xa, out1, part);
    reduce_tanh<<<256,  256, 0, stream>>>(part, out0);
}

// Round 6
// 214.961 us; speedup vs baseline: 2.3370x; 2.3370x over previous
//
#include <hip/hip_runtime.h>
#include <cstdint>
#include <cstddef>

typedef unsigned short u16;
typedef unsigned int   u32;
using short8 = __attribute__((ext_vector_type(8))) short;
using f32x4  = __attribute__((ext_vector_type(4))) float;

// B=8, N=8192, H=256, A=64 (F=320), S=32
#define NB    8
#define NN    8192
#define HH    256
#define FF    320
#define SS    32
#define NROWS 65536
#define NCH   64            // pooling K-split chunks (128 n each)

__device__ __forceinline__ u16 f2bf(float f) {          // exact RNE (prep only)
    union { float f; u32 u; } v; v.f = f;
    u32 r = v.u + 0x7fffu + ((v.u >> 16) & 1u);
    return (u16)(r >> 16);
}
// round-half-up bf16 pack: (hi.bf16 << 16) | lo.bf16 in 3 VALU ops
__device__ __forceinline__ u32 pk2h(float lo, float hi) {
    union { float f; u32 u; } a, b; a.f = lo; b.f = hi;
    return __builtin_amdgcn_perm(b.u + 0x8000u, a.u + 0x8000u, 0x07060302u);
}
__device__ __forceinline__ short8 pack8(float4 a, float4 b) {
    union { u32 u[4]; short8 s; } r;
    r.u[0] = pk2h(a.x, a.y); r.u[1] = pk2h(a.z, a.w);
    r.u[2] = pk2h(b.x, b.y); r.u[3] = pk2h(b.z, b.w);
    return r.s;
}

// ---------------- prep: cast Wi,Wj to bf16 (concat, exact RNE) ----------------
__global__ __launch_bounds__(256) void prep_w(const float* __restrict__ Wi,
                                              const float* __restrict__ Wj,
                                              u16* __restrict__ Wb) {
    int idx = blockIdx.x * 256 + threadIdx.x;       // 0..163839
    float v = (idx < 81920) ? Wi[idx] : Wj[idx - 81920];
    Wb[idx] = f2bf(v);
}

// ---------------- cast x fp32 -> bf16 (streaming, 2560 blocks x 256 thr x 4 groups) ----------------
__global__ __launch_bounds__(256) void cast_x(const float* __restrict__ x,
                                              u16* __restrict__ xb) {
    int t = blockIdx.x * 256 + threadIdx.x;          // 0..655359
    #pragma unroll
    for (int i = 0; i < 4; ++i) {
        size_t g = (size_t)i * 655360 + t;           // group of 8 floats
        float4 a = *reinterpret_cast<const float4*>(x + g * 8);
        float4 b = *reinterpret_cast<const float4*>(x + g * 8 + 4);
        *reinterpret_cast<short8*>(xb + g * 8) = pack8(a, b);
    }
}

// ---------------- kernel 1 (fast path): gated features + norm^2 partials, bf16 A ----------------
// 512 thr (8 waves), 256 rows x 128 cols; wave = 32 rows (2 mt). B full-K LDS (80 KB, one
// barrier). A: bf16 short8 direct loads, TRUE dist-3 ring (32 VGPR). acc 64 AGPR. 4 waves/SIMD.
__global__ __launch_bounds__(512, 4) void gemm_gate_pre(
    const u16* __restrict__ xbg, const u16* __restrict__ Wb,
    const float* __restrict__ bi, const float* __restrict__ bj,
    u16* __restrict__ xa, float* __restrict__ normsq_p)
{
    __shared__ u16 lB[5 * 8192];      // [kt][row 0..127][swizzled k-slot*8], 81920 B

    const int bx   = blockIdx.x;
    const int xcd  = bx & 7;
    const int ht   = (bx >> 3) & 3;
    const int slot = bx >> 5;         // 0..31
    const int mb   = xcd + slot * 8;  // 0..255
    const int m0   = mb * 256;
    const int h0   = ht * 64;
    const int b_idx = m0 >> 13;
    const int n0    = m0 & 8191;

    const int tid  = threadIdx.x;
    const int w    = tid >> 6;        // 0..7
    const int lane = tid & 63;
    const int quad = lane >> 4;
    const int l15  = lane & 15;

    // ---- one-time B load: 5 kt x 2 issues per wave ----
    {
        const int rsub = lane >> 3;                 // 0..7
        const int kg   = (lane & 7) ^ rsub;         // XOR swizzle
        #pragma unroll
        for (int kt = 0; kt < 5; ++kt) {
            #pragma unroll
            for (int j = 0; j < 2; ++j) {
                int sl  = w * 2 + j;                // 0..15
                int row = sl * 8 + rsub;            // 0..127
                int mat = row >> 6, hl = row & 63;
                const u16* gsrc = Wb + mat * 81920 + (size_t)(h0 + hl) * FF + kt * 64 + kg * 8;
                u16* ldst = &lB[kt * 8192 + sl * 512];
                __builtin_amdgcn_global_load_lds(
                    (const __attribute__((address_space(1))) void*)gsrc,
                    (__attribute__((address_space(3))) void*)ldst, 16, 0, 0);
            }
        }
    }

    const u16* xr0 = xbg + (size_t)(m0 + w * 32 + l15) * FF + quad * 8;
    const u16* xr1 = xr0 + 16 * FF;

    f32x4 acc[8][2];                  // [col/16][mt]
    #pragma unroll
    for (int a = 0; a < 8; ++a)
        #pragma unroll
        for (int m = 0; m < 2; ++m) acc[a][m] = (f32x4){0.f, 0.f, 0.f, 0.f};

    short8 af[4][2];                  // ring-4, dist-3
    #pragma unroll
    for (int s = 0; s < 3; ++s) {
        af[s][0] = *reinterpret_cast<const short8*>(xr0 + s * 32);
        af[s][1] = *reinterpret_cast<const short8*>(xr1 + s * 32);
    }

    __syncthreads();                  // B resident

    #pragma unroll
    for (int ks = 0; ks < 10; ++ks) {
        const int kt  = ks >> 1, kk = ks & 1;
        const int cur = ks & 3;
        if (ks < 7) {
            const int nx = (ks + 3) & 3;
            af[nx][0] = *reinterpret_cast<const short8*>(xr0 + (ks + 3) * 32);
            af[nx][1] = *reinterpret_cast<const short8*>(xr1 + (ks + 3) * 32);
        }
        #pragma unroll
        for (int mn = 0; mn < 8; ++mn) {
            int c = mn * 16 + l15;
            short8 bv = *reinterpret_cast<const short8*>(
                &lB[kt * 8192 + c * 64 + (((kk * 4 + quad) ^ (c & 7)) << 3)]);
            acc[mn][0] = __builtin_amdgcn_mfma_f32_16x16x32_bf16(af[cur][0], bv, acc[mn][0], 0, 0, 0);
            acc[mn][1] = __builtin_amdgcn_mfma_f32_16x16x32_bf16(af[cur][1], bv, acc[mn][1], 0, 0, 0);
        }
    }

    // ---- epilogue: gate, store xa [b][h][n], norm^2 partials (no atomics) ----
    float s0[2][4];
    #pragma unroll
    for (int mt = 0; mt < 2; ++mt)
        #pragma unroll
        for (int r = 0; r < 4; ++r) s0[mt][r] = 0.f;

    #pragma unroll
    for (int hq = 0; hq < 4; ++hq) {
        int h = h0 + hq * 16 + l15;
        float bi_v = bi[h], bj_v = bj[h];
        #pragma unroll
        for (int mt = 0; mt < 2; ++mt) {
            float xall[4];
            #pragma unroll
            for (int r = 0; r < 4; ++r) {
                float yi = acc[hq][mt][r] + bi_v;
                float yj = acc[hq + 4][mt][r] + bj_v;
                float sg = 1.f / (1.f + __expf(-yi));
                float e2 = __expf(-2.f * yj);
                float th = (1.f - e2) / (1.f + e2);
                float xv = sg * th;
                xall[r] = xv;
                s0[mt][r] += xv * xv;
            }
            uint2 pk;
            pk.x = pk2h(xall[0], xall[1]);
            pk.y = pk2h(xall[2], xall[3]);
            size_t o = (size_t)b_idx * ((size_t)HH * NN) + (size_t)h * NN
                     + (size_t)(n0 + w * 32 + mt * 16 + quad * 4);
            *reinterpret_cast<uint2*>(&xa[o]) = pk;
        }
    }
    #pragma unroll
    for (int m = 1; m <= 8; m <<= 1) {
        #pragma unroll
        for (int mt = 0; mt < 2; ++mt)
            #pragma unroll
            for (int r = 0; r < 4; ++r)
                s0[mt][r] += __shfl_xor(s0[mt][r], m, 64);
    }
    if (l15 == 0) {
        #pragma unroll
        for (int mt = 0; mt < 2; ++mt)
            #pragma unroll
            for (int r = 0; r < 4; ++r)
                normsq_p[ht * NROWS + m0 + w * 32 + mt * 16 + quad * 4 + r] = s0[mt][r];
    }
}

// ---------------- kernel 1 (fallback, no xb space): round-4 fp32-A version ----------------
__global__ __launch_bounds__(512, 4) void gemm_gate_f32(
    const float* __restrict__ x, const u16* __restrict__ Wb,
    const float* __restrict__ bi, const float* __restrict__ bj,
    u16* __restrict__ xa, float* __restrict__ normsq_p)
{
    __shared__ u16 lB[5 * 8192];

    const int bx   = blockIdx.x;
    const int xcd  = bx & 7;
    const int ht   = (bx >> 3) & 3;
    const int slot = bx >> 5;
    const int mb   = xcd + slot * 8;
    const int m0   = mb * 256;
    const int h0   = ht * 64;
    const int b_idx = m0 >> 13;
    const int n0    = m0 & 8191;

    const int tid  = threadIdx.x;
    const int w    = tid >> 6;
    const int lane = tid & 63;
    const int quad = lane >> 4;
    const int l15  = lane & 15;

    {
        const int rsub = lane >> 3;
        const int kg   = (lane & 7) ^ rsub;
        #pragma unroll
        for (int kt = 0; kt < 5; ++kt) {
            #pragma unroll
            for (int j = 0; j < 2; ++j) {
                int sl  = w * 2 + j;
                int row = sl * 8 + rsub;
                int mat = row >> 6, hl = row & 63;
                const u16* gsrc = Wb + mat * 81920 + (size_t)(h0 + hl) * FF + kt * 64 + kg * 8;
                u16* ldst = &lB[kt * 8192 + sl * 512];
                __builtin_amdgcn_global_load_lds(
                    (const __attribute__((address_space(1))) void*)gsrc,
                    (__attribute__((address_space(3))) void*)ldst, 16, 0, 0);
            }
        }
    }

    const float* xb = x + (size_t)(m0 + w * 32 + l15) * FF + quad * 8;

    f32x4 acc[8][2];
    #pragma unroll
    for (int a = 0; a < 8; ++a)
        #pragma unroll
        for (int m = 0; m < 2; ++m) acc[a][m] = (f32x4){0.f, 0.f, 0.f, 0.f};

    float4 pre[3][2][2];
    #pragma unroll
    for (int s = 0; s < 2; ++s)
        #pragma unroll
        for (int mt = 0; mt < 2; ++mt) {
            pre[s][mt][0] = *reinterpret_cast<const float4*>(xb + mt * 16 * FF + s * 32);
            pre[s][mt][1] = *reinterpret_cast<const float4*>(xb + mt * 16 * FF + s * 32 + 4);
        }

    __syncthreads();

    #pragma unroll
    for (int ks = 0; ks < 10; ++ks) {
        const int kt  = ks >> 1, kk = ks & 1;
        const int cur = ks % 3;
        if (ks < 8) {
            const int nx = (ks + 2) % 3;
            const int f  = (ks + 2) * 32;
            #pragma unroll
            for (int mt = 0; mt < 2; ++mt) {
                pre[nx][mt][0] = *reinterpret_cast<const float4*>(xb + mt * 16 * FF + f);
                pre[nx][mt][1] = *reinterpret_cast<const float4*>(xb + mt * 16 * FF + f + 4);
            }
        }
        short8 af0 = pack8(pre[cur][0][0], pre[cur][0][1]);
        short8 af1 = pack8(pre[cur][1][0], pre[cur][1][1]);
        #pragma unroll
        for (int mn = 0; mn < 8; ++mn) {
            int c = mn * 16 + l15;
            short8 bv = *reinterpret_cast<const short8*>(
                &lB[kt * 8192 + c * 64 + (((kk * 4 + quad) ^ (c & 7)) << 3)]);
            acc[mn][0] = __builtin_amdgcn_mfma_f32_16x16x32_bf16(af0, bv, acc[mn][0], 0, 0, 0);
            acc[mn][1] = __builtin_amdgcn_mfma_f32_16x16x32_bf16(af1, bv, acc[mn][1], 0, 0, 0);
        }
    }

    float s0[2][4];
    #pragma unroll
    for (int mt = 0; mt < 2; ++mt)
        #pragma unroll
        for (int r = 0; r < 4; ++r) s0[mt][r] = 0.f;

    #pragma unroll
    for (int hq = 0; hq < 4; ++hq) {
        int h = h0 + hq * 16 + l15;
        float bi_v = bi[h], bj_v = bj[h];
        #pragma unroll
        for (int mt = 0; mt < 2; ++mt) {
            float xall[4];
            #pragma unroll
            for (int r = 0; r < 4; ++r) {
                float yi = acc[hq][mt][r] + bi_v;
                float yj = acc[hq + 4][mt][r] + bj_v;
                float sg = 1.f / (1.f + __expf(-yi));
                float e2 = __expf(-2.f * yj);
                float th = (1.f - e2) / (1.f + e2);
                float xv = sg * th;
                xall[r] = xv;
                s0[mt][r] += xv * xv;
            }
            uint2 pk;
            pk.x = pk2h(xall[0], xall[1]);
            pk.y = pk2h(xall[2], xall[3]);
            size_t o = (size_t)b_idx * ((size_t)HH * NN) + (size_t)h * NN
                     + (size_t)(n0 + w * 32 + mt * 16 + quad * 4);
            *reinterpret_cast<uint2*>(&xa[o]) = pk;
        }
    }
    #pragma unroll
    for (int m = 1; m <= 8; m <<= 1) {
        #pragma unroll
        for (int mt = 0; mt < 2; ++mt)
            #pragma unroll
            for (int r = 0; r < 4; ++r)
                s0[mt][r] += __shfl_xor(s0[mt][r], m, 64);
    }
    if (l15 == 0) {
        #pragma unroll
        for (int mt = 0; mt < 2; ++mt)
            #pragma unroll
            for (int r = 0; r < 4; ++r)
                normsq_p[ht * NROWS + m0 + w * 32 + mt * 16 + quad * 4 + r] = s0[mt][r];
    }
}

// ---------------- kernel 2: masked softmax over N per (b,s) -> out1 fp32 ----------------
__global__ __launch_bounds__(1024) void softmax_k(
    const float* __restrict__ nm, const float* __restrict__ normsq_p,
    float* __restrict__ out1)
{
    __shared__ float red[16];
    int bs = blockIdx.x;                 // 0..255
    int b  = bs >> 5;
    const float* src = nm + (size_t)bs * NN;
    float* dst       = out1 + (size_t)bs * NN;
    const float* ns  = normsq_p + (size_t)b * NN;
    int tid = threadIdx.x;
    float e[8];
    float sum = 0.f;
    #pragma unroll
    for (int i = 0; i < 8; ++i) {
        int n = i * 1024 + tid;
        float nsq = ns[n] + ns[n + NROWS] + ns[n + 2 * NROWS] + ns[n + 3 * NROWS];
        float logit = src[n] * sqrtf(nsq);
        float v = (logit > 0.f) ? __expf(logit) : 0.f;
        e[i] = v;
        sum += v;
    }
    #pragma unroll
    for (int m = 1; m <= 32; m <<= 1) sum += __shfl_xor(sum, m, 64);
    int w = tid >> 6, lane = tid & 63;
    if (lane == 0) red[w] = sum;
    __syncthreads();
    float part = 0.f;
    #pragma unroll
    for (int j = 0; j < 16; ++j) part += red[j];
    float inv = (part > 0.f) ? (1.f / part) : 0.f;
    #pragma unroll
    for (int i = 0; i < 8; ++i) dst[i * 1024 + tid] = e[i] * inv;
}

// ---------------- kernel 3: pooling GEMM partials over 128-n chunks ----------------
__global__ __launch_bounds__(256) void pooled_k(
    const u16* __restrict__ xa, const float* __restrict__ wgt,
    float* __restrict__ part)
{
    __shared__ u16 lw[32 * 136];         // [s][k] stride 136 shorts
    int bx = blockIdx.x;                 // 512
    int b  = bx >> 6, c = bx & 63;
    int n0 = c * 128;
    int tid = threadIdx.x, w = tid >> 6, lane = tid & 63, quad = lane >> 4, l15 = lane & 15;

    const u16* ab = xa + (size_t)b * ((size_t)HH * NN) + n0;

    short8 av[2][4];
    #pragma unroll
    for (int htl = 0; htl < 4; ++htl) {
        int h = w * 64 + htl * 16 + l15;
        av[0][htl] = *reinterpret_cast<const short8*>(ab + (size_t)h * NN + quad * 8);
    }

    {
        int s  = tid >> 3;
        int jq = (tid & 7) * 16;
        const float* src = wgt + (size_t)(b * SS + s) * NN + n0 + jq;
        #pragma unroll
        for (int q = 0; q < 4; ++q) {
            float4 v = *reinterpret_cast<const float4*>(src + q * 4);
            uint2 pk;
            pk.x = pk2h(v.x, v.y);
            pk.y = pk2h(v.z, v.w);
            *reinterpret_cast<uint2*>(&lw[s * 136 + jq + q * 4]) = pk;
        }
    }
    __syncthreads();

    f32x4 acc[4][2];
    #pragma unroll
    for (int a = 0; a < 4; ++a)
        #pragma unroll
        for (int s = 0; s < 2; ++s) acc[a][s] = (f32x4){0.f, 0.f, 0.f, 0.f};

    #pragma unroll
    for (int ks = 0; ks < 4; ++ks) {
        const int cur = ks & 1, nxt = cur ^ 1;
        if (ks < 3) {
            #pragma unroll
            for (int htl = 0; htl < 4; ++htl) {
                int h = w * 64 + htl * 16 + l15;
                av[nxt][htl] = *reinterpret_cast<const short8*>(
                    ab + (size_t)h * NN + (ks + 1) * 32 + quad * 8);
            }
        }
        #pragma unroll
        for (int st = 0; st < 2; ++st) {
            int s = st * 16 + l15;
            short8 bv = *reinterpret_cast<const short8*>(&lw[s * 136 + ks * 32 + quad * 8]);
            #pragma unroll
            for (int htl = 0; htl < 4; ++htl)
                acc[htl][st] = __builtin_amdgcn_mfma_f32_16x16x32_bf16(av[cur][htl], bv, acc[htl][st], 0, 0, 0);
        }
    }
    float* pb = part + (size_t)(b * NCH + c) * 8192;   // [s*256 + h]
    #pragma unroll
    for (int htl = 0; htl < 4; ++htl) {
        #pragma unroll
        for (int st = 0; st < 2; ++st) {
            int h = w * 64 + htl * 16 + quad * 4;
            int s = st * 16 + l15;
            *reinterpret_cast<f32x4*>(&pb[s * 256 + h]) = acc[htl][st];
        }
    }
}

// ---------------- kernel 4: reduce partials over 64 chunks + tanh -> out0 ----------------
__global__ __launch_bounds__(256) void reduce_tanh(const float* __restrict__ part,
                                                   float* __restrict__ out0)
{
    int gid = blockIdx.x * 256 + threadIdx.x;   // 0..65535 = b*8192 + s*256 + h
    int b = gid >> 13, r = gid & 8191;
    const float* p = part + (size_t)b * NCH * 8192 + r;
    float s = 0.f;
    #pragma unroll
    for (int c = 0; c < NCH; ++c) s += p[(size_t)c * 8192];
    out0[gid] = tanhf(s);
}

extern "C" void kernel_launch(void* const* d_in, const int* in_sizes, int n_in,
                              void* d_out, int out_size, void* d_ws, size_t ws_size,
                              hipStream_t stream) {
    const float* x  = (const float*)d_in[0];
    const float* nm = (const float*)d_in[1];
    const float* Wi = (const float*)d_in[2];
    const float* bi = (const float*)d_in[3];
    const float* Wj = (const float*)d_in[4];
    const float* bj = (const float*)d_in[5];
    float* out0 = (float*)d_out;
    float* out1 = out0 + NB * SS * HH;           // 65536

    char* ws = (char*)d_ws;
    size_t off = 0;
    u16*   Wb       = (u16*)(ws + off);  off += 327680;
    u16*   xa       = (u16*)(ws + off);  off += 33554432;
    float* normsq_p = (float*)(ws + off); off += 1048576;   // [4][65536]
    float* part     = (float*)(ws + off); off += 16777216;
    u16*   xb       = (u16*)(ws + off);
    const size_t need_fast = off + 41943040;                 // + xb bf16 [65536][320]

    prep_w<<<640, 256, 0, stream>>>(Wi, Wj, Wb);
    if (ws_size >= need_fast) {
        cast_x       <<<2560, 256, 0, stream>>>(x, xb);
        gemm_gate_pre<<<1024, 512, 0, stream>>>(xb, Wb, bi, bj, xa, normsq_p);
    } else {
        gemm_gate_f32<<<1024, 512, 0, stream>>>(x, Wb, bi, bj, xa, normsq_p);
    }
    softmax_k  <<<256, 1024, 0, stream>>>(nm, normsq_p, out1);
    pooled_k   <<<512,  256, 0, stream>>>(xa, out1, part);
    reduce_tanh<<<256,  256, 0, stream>>>(part, out0);
}

// Round 7
// 211.678 us; speedup vs baseline: 2.3732x; 1.0155x over previous
//
#include <hip/hip_runtime.h>
#include <cstdint>
#include <cstddef>

typedef unsigned short u16;
typedef unsigned int   u32;
using short8 = __attribute__((ext_vector_type(8))) short;
using f32x4  = __attribute__((ext_vector_type(4))) float;

// B=8, N=8192, H=256, A=64 (F=320), S=32
#define NB    8
#define NN    8192
#define HH    256
#define FF    320
#define SS    32
#define NROWS 65536
#define NCH   32            // pooling K-split chunks (256 n each)

__device__ __forceinline__ u16 f2bf(float f) {          // exact RNE (prep only)
    union { float f; u32 u; } v; v.f = f;
    u32 r = v.u + 0x7fffu + ((v.u >> 16) & 1u);
    return (u16)(r >> 16);
}
// round-half-up bf16 pack: (hi.bf16 << 16) | lo.bf16 in 3 VALU ops
__device__ __forceinline__ u32 pk2h(float lo, float hi) {
    union { float f; u32 u; } a, b; a.f = lo; b.f = hi;
    return __builtin_amdgcn_perm(b.u + 0x8000u, a.u + 0x8000u, 0x07060302u);
}
__device__ __forceinline__ short8 pack8(float4 a, float4 b) {
    union { u32 u[4]; short8 s; } r;
    r.u[0] = pk2h(a.x, a.y); r.u[1] = pk2h(a.z, a.w);
    r.u[2] = pk2h(b.x, b.y); r.u[3] = pk2h(b.z, b.w);
    return r.s;
}

// ---------------- prep: W cast (blocks 0..639) + x cast (blocks 640..3199) ----------------
__global__ __launch_bounds__(256) void prep_all(const float* __restrict__ Wi,
                                                const float* __restrict__ Wj,
                                                const float* __restrict__ x,
                                                u16* __restrict__ Wb,
                                                u16* __restrict__ xb) {
    int bx = blockIdx.x;
    if (bx < 640) {
        int idx = bx * 256 + threadIdx.x;            // 0..163839
        float v = (idx < 81920) ? Wi[idx] : Wj[idx - 81920];
        Wb[idx] = f2bf(v);
    } else {
        int t = (bx - 640) * 256 + threadIdx.x;      // 0..655359
        #pragma unroll
        for (int i = 0; i < 4; ++i) {
            size_t g = (size_t)i * 655360 + t;       // group of 8 floats
            float4 a = *reinterpret_cast<const float4*>(x + g * 8);
            float4 b = *reinterpret_cast<const float4*>(x + g * 8 + 4);
            *reinterpret_cast<short8*>(xb + g * 8) = pack8(a, b);
        }
    }
}

// ---------------- kernel 1: gated features + norm^2 partials (bf16 A) ----------------
// 512 thr (8 waves), block = 256 rows x 128 cols (2 mats x 64 h).
// Wave = 64 rows (rg=w>>1) x 32 cols-of-each-matrix (cg=w&1): owns yi AND yj for its
// (64 rows x 32 h) -> no epilogue exchange. B-frag shared over 64 rows: LDS traffic
// halved vs 32-row waves. acc 64 AGPR + A ring-2 (32 VGPR) fits 4 waves/SIMD.
__global__ __launch_bounds__(512, 4) void gemm_gate_pre(
    const u16* __restrict__ xbg, const u16* __restrict__ Wb,
    const float* __restrict__ bi, const float* __restrict__ bj,
    u16* __restrict__ xa, float* __restrict__ normsq_p)
{
    __shared__ u16 lB[5 * 8192];      // [kt][row 0..127][swizzled k-slot*8], 81920 B

    const int bx   = blockIdx.x;
    const int xcd  = bx & 7;
    const int ht   = (bx >> 3) & 3;
    const int slot = bx >> 5;         // 0..31
    const int mb   = xcd + slot * 8;  // 0..255
    const int m0   = mb * 256;
    const int h0   = ht * 64;
    const int b_idx = m0 >> 13;
    const int n0    = m0 & 8191;

    const int tid  = threadIdx.x;
    const int w    = tid >> 6;        // 0..7
    const int lane = tid & 63;
    const int quad = lane >> 4;
    const int l15  = lane & 15;
    const int rg   = w >> 1;          // row-group 0..3 (64 rows each)
    const int cg   = w & 1;           // col-group 0..1 (32 h of each matrix)

    // ---- one-time B load: 5 kt x 2 issues per wave ----
    {
        const int rsub = lane >> 3;                 // 0..7
        const int kg   = (lane & 7) ^ rsub;         // XOR swizzle
        #pragma unroll
        for (int kt = 0; kt < 5; ++kt) {
            #pragma unroll
            for (int j = 0; j < 2; ++j) {
                int sl  = w * 2 + j;                // 0..15
                int row = sl * 8 + rsub;            // 0..127
                int mat = row >> 6, hl = row & 63;
                const u16* gsrc = Wb + mat * 81920 + (size_t)(h0 + hl) * FF + kt * 64 + kg * 8;
                u16* ldst = &lB[kt * 8192 + sl * 512];
                __builtin_amdgcn_global_load_lds(
                    (const __attribute__((address_space(1))) void*)gsrc,
                    (__attribute__((address_space(3))) void*)ldst, 16, 0, 0);
            }
        }
    }

    // A rows: m0 + rg*64 + mt*16 + l15, k = ks*32 + quad*8
    const u16* xr = xbg + (size_t)(m0 + rg * 64 + l15) * FF + quad * 8;

    f32x4 acc[4][4];                  // [mn][mt]; mn 0,1 = Wi tiles, 2,3 = Wj tiles
    #pragma unroll
    for (int a = 0; a < 4; ++a)
        #pragma unroll
        for (int m = 0; m < 4; ++m) acc[a][m] = (f32x4){0.f, 0.f, 0.f, 0.f};

    short8 af[2][4];                  // ring-2 (dist-1)
    #pragma unroll
    for (int mt = 0; mt < 4; ++mt)
        af[0][mt] = *reinterpret_cast<const short8*>(xr + mt * 16 * FF);

    // wave's B LDS row bases: Wi h0+cg*32 (+16), Wj same
    const int cb0 = cg * 32, cb1 = cg * 32 + 16, cb2 = 64 + cg * 32, cb3 = 64 + cg * 32 + 16;

    __syncthreads();                  // B resident

    #pragma unroll
    for (int ks = 0; ks < 10; ++ks) {
        const int kt  = ks >> 1, kk = ks & 1;
        const int cur = ks & 1, nxt = cur ^ 1;
        if (ks < 9) {
            #pragma unroll
            for (int mt = 0; mt < 4; ++mt)
                af[nxt][mt] = *reinterpret_cast<const short8*>(xr + mt * 16 * FF + (ks + 1) * 32);
        }
        const int cbs[4] = {cb0, cb1, cb2, cb3};
        #pragma unroll
        for (int mn = 0; mn < 4; ++mn) {
            int c = cbs[mn] + l15;
            short8 bv = *reinterpret_cast<const short8*>(
                &lB[kt * 8192 + c * 64 + (((kk * 4 + quad) ^ (c & 7)) << 3)]);
            #pragma unroll
            for (int mt = 0; mt < 4; ++mt)
                acc[mn][mt] = __builtin_amdgcn_mfma_f32_16x16x32_bf16(af[cur][mt], bv, acc[mn][mt], 0, 0, 0);
        }
    }

    // ---- epilogue: gate, store xa [b][h][n], norm^2 partials (8 slots, no atomics) ----
    float s0[4][4];                   // [mt][r], summed over this wave's 32 h
    #pragma unroll
    for (int mt = 0; mt < 4; ++mt)
        #pragma unroll
        for (int r = 0; r < 4; ++r) s0[mt][r] = 0.f;

    #pragma unroll
    for (int hq = 0; hq < 2; ++hq) {
        int h = h0 + cg * 32 + hq * 16 + l15;
        float bi_v = bi[h], bj_v = bj[h];
        #pragma unroll
        for (int mt = 0; mt < 4; ++mt) {
            float xall[4];
            #pragma unroll
            for (int r = 0; r < 4; ++r) {
                float yi = acc[hq][mt][r] + bi_v;
                float yj = acc[hq + 2][mt][r] + bj_v;
                float sg = 1.f / (1.f + __expf(-yi));
                float e2 = __expf(-2.f * yj);
                float th = (1.f - e2) / (1.f + e2);
                float xv = sg * th;
                xall[r] = xv;
                s0[mt][r] += xv * xv;
            }
            uint2 pk;
            pk.x = pk2h(xall[0], xall[1]);
            pk.y = pk2h(xall[2], xall[3]);
            size_t o = (size_t)b_idx * ((size_t)HH * NN) + (size_t)h * NN
                     + (size_t)(n0 + rg * 64 + mt * 16 + quad * 4);
            *reinterpret_cast<uint2*>(&xa[o]) = pk;
        }
    }
    #pragma unroll
    for (int m = 1; m <= 8; m <<= 1) {
        #pragma unroll
        for (int mt = 0; mt < 4; ++mt)
            #pragma unroll
            for (int r = 0; r < 4; ++r)
                s0[mt][r] += __shfl_xor(s0[mt][r], m, 64);
    }
    if (l15 == 0) {
        #pragma unroll
        for (int mt = 0; mt < 4; ++mt)
            #pragma unroll
            for (int r = 0; r < 4; ++r)
                normsq_p[(ht * 2 + cg) * NROWS + m0 + rg * 64 + mt * 16 + quad * 4 + r] = s0[mt][r];
    }
}

// ---------------- fallback (no xb space): round-4 fp32-A version, 4 partial slots ----------------
__global__ __launch_bounds__(512, 4) void gemm_gate_f32(
    const float* __restrict__ x, const u16* __restrict__ Wb,
    const float* __restrict__ bi, const float* __restrict__ bj,
    u16* __restrict__ xa, float* __restrict__ normsq_p)
{
    __shared__ u16 lB[5 * 8192];

    const int bx   = blockIdx.x;
    const int xcd  = bx & 7;
    const int ht   = (bx >> 3) & 3;
    const int slot = bx >> 5;
    const int mb   = xcd + slot * 8;
    const int m0   = mb * 256;
    const int h0   = ht * 64;
    const int b_idx = m0 >> 13;
    const int n0    = m0 & 8191;

    const int tid  = threadIdx.x;
    const int w    = tid >> 6;
    const int lane = tid & 63;
    const int quad = lane >> 4;
    const int l15  = lane & 15;

    {
        const int rsub = lane >> 3;
        const int kg   = (lane & 7) ^ rsub;
        #pragma unroll
        for (int kt = 0; kt < 5; ++kt) {
            #pragma unroll
            for (int j = 0; j < 2; ++j) {
                int sl  = w * 2 + j;
                int row = sl * 8 + rsub;
                int mat = row >> 6, hl = row & 63;
                const u16* gsrc = Wb + mat * 81920 + (size_t)(h0 + hl) * FF + kt * 64 + kg * 8;
                u16* ldst = &lB[kt * 8192 + sl * 512];
                __builtin_amdgcn_global_load_lds(
                    (const __attribute__((address_space(1))) void*)gsrc,
                    (__attribute__((address_space(3))) void*)ldst, 16, 0, 0);
            }
        }
    }

    const float* xb = x + (size_t)(m0 + w * 32 + l15) * FF + quad * 8;

    f32x4 acc[8][2];
    #pragma unroll
    for (int a = 0; a < 8; ++a)
        #pragma unroll
        for (int m = 0; m < 2; ++m) acc[a][m] = (f32x4){0.f, 0.f, 0.f, 0.f};

    float4 pre[3][2][2];
    #pragma unroll
    for (int s = 0; s < 2; ++s)
        #pragma unroll
        for (int mt = 0; mt < 2; ++mt) {
            pre[s][mt][0] = *reinterpret_cast<const float4*>(xb + mt * 16 * FF + s * 32);
            pre[s][mt][1] = *reinterpret_cast<const float4*>(xb + mt * 16 * FF + s * 32 + 4);
        }

    __syncthreads();

    #pragma unroll
    for (int ks = 0; ks < 10; ++ks) {
        const int kt  = ks >> 1, kk = ks & 1;
        const int cur = ks % 3;
        if (ks < 8) {
            const int nx = (ks + 2) % 3;
            const int f  = (ks + 2) * 32;
            #pragma unroll
            for (int mt = 0; mt < 2; ++mt) {
                pre[nx][mt][0] = *reinterpret_cast<const float4*>(xb + mt * 16 * FF + f);
                pre[nx][mt][1] = *reinterpret_cast<const float4*>(xb + mt * 16 * FF + f + 4);
            }
        }
        short8 af0 = pack8(pre[cur][0][0], pre[cur][0][1]);
        short8 af1 = pack8(pre[cur][1][0], pre[cur][1][1]);
        #pragma unroll
        for (int mn = 0; mn < 8; ++mn) {
            int c = mn * 16 + l15;
            short8 bv = *reinterpret_cast<const short8*>(
                &lB[kt * 8192 + c * 64 + (((kk * 4 + quad) ^ (c & 7)) << 3)]);
            acc[mn][0] = __builtin_amdgcn_mfma_f32_16x16x32_bf16(af0, bv, acc[mn][0], 0, 0, 0);
            acc[mn][1] = __builtin_amdgcn_mfma_f32_16x16x32_bf16(af1, bv, acc[mn][1], 0, 0, 0);
        }
    }

    float s0[2][4];
    #pragma unroll
    for (int mt = 0; mt < 2; ++mt)
        #pragma unroll
        for (int r = 0; r < 4; ++r) s0[mt][r] = 0.f;

    #pragma unroll
    for (int hq = 0; hq < 4; ++hq) {
        int h = h0 + hq * 16 + l15;
        float bi_v = bi[h], bj_v = bj[h];
        #pragma unroll
        for (int mt = 0; mt < 2; ++mt) {
            float xall[4];
            #pragma unroll
            for (int r = 0; r < 4; ++r) {
                float yi = acc[hq][mt][r] + bi_v;
                float yj = acc[hq + 4][mt][r] + bj_v;
                float sg = 1.f / (1.f + __expf(-yi));
                float e2 = __expf(-2.f * yj);
                float th = (1.f - e2) / (1.f + e2);
                float xv = sg * th;
                xall[r] = xv;
                s0[mt][r] += xv * xv;
            }
            uint2 pk;
            pk.x = pk2h(xall[0], xall[1]);
            pk.y = pk2h(xall[2], xall[3]);
            size_t o = (size_t)b_idx * ((size_t)HH * NN) + (size_t)h * NN
                     + (size_t)(n0 + w * 32 + mt * 16 + quad * 4);
            *reinterpret_cast<uint2*>(&xa[o]) = pk;
        }
    }
    #pragma unroll
    for (int m = 1; m <= 8; m <<= 1) {
        #pragma unroll
        for (int mt = 0; mt < 2; ++mt)
            #pragma unroll
            for (int r = 0; r < 4; ++r)
                s0[mt][r] += __shfl_xor(s0[mt][r], m, 64);
    }
    if (l15 == 0) {
        #pragma unroll
        for (int mt = 0; mt < 2; ++mt)
            #pragma unroll
            for (int r = 0; r < 4; ++r)
                normsq_p[ht * NROWS + m0 + w * 32 + mt * 16 + quad * 4 + r] = s0[mt][r];
    }
}

// ---------------- kernel 2: masked softmax over N per (b,s) -> out1 fp32 ----------------
__global__ __launch_bounds__(1024) void softmax_k(
    const float* __restrict__ nm, const float* __restrict__ normsq_p,
    float* __restrict__ out1)
{
    __shared__ float red[16];
    int bs = blockIdx.x;                 // 0..255
    int b  = bs >> 5;
    const float* src = nm + (size_t)bs * NN;
    float* dst       = out1 + (size_t)bs * NN;
    const float* ns  = normsq_p + (size_t)b * NN;
    int tid = threadIdx.x;
    float e[8];
    float sum = 0.f;
    #pragma unroll
    for (int i = 0; i < 8; ++i) {
        int n = i * 1024 + tid;
        float nsq = 0.f;
        #pragma unroll
        for (int j = 0; j < 8; ++j) nsq += ns[n + j * NROWS];
        float logit = src[n] * sqrtf(nsq);
        float v = (logit > 0.f) ? __expf(logit) : 0.f;
        e[i] = v;
        sum += v;
    }
    #pragma unroll
    for (int m = 1; m <= 32; m <<= 1) sum += __shfl_xor(sum, m, 64);
    int w = tid >> 6, lane = tid & 63;
    if (lane == 0) red[w] = sum;
    __syncthreads();
    float part = 0.f;
    #pragma unroll
    for (int j = 0; j < 16; ++j) part += red[j];
    float inv = (part > 0.f) ? (1.f / part) : 0.f;
    #pragma unroll
    for (int i = 0; i < 8; ++i) dst[i * 1024 + tid] = e[i] * inv;
}

// ---------------- kernel 3: pooling GEMM partials over 256-n chunks ----------------
__global__ __launch_bounds__(256) void pooled_k(
    const u16* __restrict__ xa, const float* __restrict__ wgt,
    float* __restrict__ part)
{
    __shared__ u16 lw[32 * 264];         // [s][k] stride 264 shorts
    int bx = blockIdx.x;                 // 256
    int b  = bx >> 5, c = bx & 31;
    int n0 = c * 256;
    int tid = threadIdx.x, w = tid >> 6, lane = tid & 63, quad = lane >> 4, l15 = lane & 15;

    const u16* ab = xa + (size_t)b * ((size_t)HH * NN) + n0;

    // prefetch ks=0 A-fragments before the barrier (independent of LDS)
    short8 av[2][4];
    #pragma unroll
    for (int htl = 0; htl < 4; ++htl) {
        int h = w * 64 + htl * 16 + l15;
        av[0][htl] = *reinterpret_cast<const short8*>(ab + (size_t)h * NN + quad * 8);
    }

    // stage weights fp32 -> bf16 (32 s x 256 n)
    {
        int s  = tid >> 3;
        int nb = (tid & 7) * 32;
        const float* src = wgt + (size_t)(b * SS + s) * NN + n0 + nb;
        #pragma unroll
        for (int q = 0; q < 8; ++q) {
            float4 v = *reinterpret_cast<const float4*>(src + q * 4);
            uint2 pk;
            pk.x = pk2h(v.x, v.y);
            pk.y = pk2h(v.z, v.w);
            *reinterpret_cast<uint2*>(&lw[s * 264 + nb + q * 4]) = pk;
        }
    }
    __syncthreads();

    f32x4 acc[4][2];
    #pragma unroll
    for (int a = 0; a < 4; ++a)
        #pragma unroll
        for (int s = 0; s < 2; ++s) acc[a][s] = (f32x4){0.f, 0.f, 0.f, 0.f};

    #pragma unroll
    for (int ks = 0; ks < 8; ++ks) {
        const int cur = ks & 1, nxt = cur ^ 1;
        if (ks < 7) {
            #pragma unroll
            for (int htl = 0; htl < 4; ++htl) {
                int h = w * 64 + htl * 16 + l15;
                av[nxt][htl] = *reinterpret_cast<const short8*>(
                    ab + (size_t)h * NN + (ks + 1) * 32 + quad * 8);
            }
        }
        #pragma unroll
        for (int st = 0; st < 2; ++st) {
            int s = st * 16 + l15;
            short8 bv = *reinterpret_cast<const short8*>(&lw[s * 264 + ks * 32 + quad * 8]);
            #pragma unroll
            for (int htl = 0; htl < 4; ++htl)
                acc[htl][st] = __builtin_amdgcn_mfma_f32_16x16x32_bf16(av[cur][htl], bv, acc[htl][st], 0, 0, 0);
        }
    }
    float* pb = part + (size_t)(b * NCH + c) * 8192;   // [s*256 + h]
    #pragma unroll
    for (int htl = 0; htl < 4; ++htl) {
        #pragma unroll
        for (int st = 0; st < 2; ++st) {
            int h = w * 64 + htl * 16 + quad * 4;
            int s = st * 16 + l15;
            *reinterpret_cast<f32x4*>(&pb[s * 256 + h]) = acc[htl][st];
        }
    }
}

// ---------------- kernel 4: reduce partials over 32 chunks + tanh -> out0 ----------------
__global__ __launch_bounds__(256) void reduce_tanh(const float* __restrict__ part,
                                                   float* __restrict__ out0)
{
    int gid = blockIdx.x * 256 + threadIdx.x;   // 0..65535 = b*8192 + s*256 + h
    int b = gid >> 13, r = gid & 8191;
    const float* p = part + (size_t)b * NCH * 8192 + r;
    float s = 0.f;
    #pragma unroll
    for (int c = 0; c < NCH; ++c) s += p[(size_t)c * 8192];
    out0[gid] = tanhf(s);
}

extern "C" void kernel_launch(void* const* d_in, const int* in_sizes, int n_in,
                              void* d_out, int out_size, void* d_ws, size_t ws_size,
                              hipStream_t stream) {
    const float* x  = (const float*)d_in[0];
    const float* nm = (const float*)d_in[1];
    const float* Wi = (const float*)d_in[2];
    const float* bi = (const float*)d_in[3];
    const float* Wj = (const float*)d_in[4];
    const float* bj = (const float*)d_in[5];
    float* out0 = (float*)d_out;
    float* out1 = out0 + NB * SS * HH;           // 65536

    char* ws = (char*)d_ws;
    size_t off = 0;
    u16*   Wb       = (u16*)(ws + off);   off += 327680;
    u16*   xa       = (u16*)(ws + off);   off += 33554432;
    float* normsq_p = (float*)(ws + off); off += 2097152;    // [8][65536]
    float* part     = (float*)(ws + off); off += 8388608;    // [8][32][8192]
    u16*   xb       = (u16*)(ws + off);
    const size_t need_fast = off + 41943040;                 // + xb bf16 [65536][320]

    if (ws_size >= need_fast) {
        prep_all     <<<3200, 256, 0, stream>>>(Wi, Wj, x, Wb, xb);
        gemm_gate_pre<<<1024, 512, 0, stream>>>(xb, Wb, bi, bj, xa, normsq_p);
    } else {
        prep_all     <<<640,  256, 0, stream>>>(Wi, Wj, x, Wb, xb);
        hipMemsetAsync(normsq_p + 4 * NROWS, 0, 4 * NROWS * sizeof(float), stream);
        gemm_gate_f32<<<1024, 512, 0, stream>>>(x, Wb, bi, bj, xa, normsq_p);
    }
    softmax_k  <<<256, 1024, 0, stream>>>(nm, normsq_p, out1);
    pooled_k   <<<256,  256, 0, stream>>>(xa, out1, part);
    reduce_tanh<<<256,  256, 0, stream>>>(part, out0);
}

// Round 8
// 206.589 us; speedup vs baseline: 2.4317x; 1.0246x over previous
//
#include <hip/hip_runtime.h>
#include <cstdint>
#include <cstddef>

typedef unsigned short u16;
typedef unsigned int   u32;
using short8 = __attribute__((ext_vector_type(8))) short;
using f32x4  = __attribute__((ext_vector_type(4))) float;

// B=8, N=8192, H=256, A=64 (F=320), S=32
#define NB    8
#define NN    8192
#define HH    256
#define FF    320
#define SS    32
#define NROWS 65536
#define NCH   32            // pooling K-split chunks (256 n each)

__device__ __forceinline__ u16 f2bf(float f) {          // exact RNE (prep only)
    union { float f; u32 u; } v; v.f = f;
    u32 r = v.u + 0x7fffu + ((v.u >> 16) & 1u);
    return (u16)(r >> 16);
}
// round-half-up bf16 pack: (hi.bf16 << 16) | lo.bf16 in 3 VALU ops
__device__ __forceinline__ u32 pk2h(float lo, float hi) {
    union { float f; u32 u; } a, b; a.f = lo; b.f = hi;
    return __builtin_amdgcn_perm(b.u + 0x8000u, a.u + 0x8000u, 0x07060302u);
}
__device__ __forceinline__ short8 pack8(float4 a, float4 b) {
    union { u32 u[4]; short8 s; } r;
    r.u[0] = pk2h(a.x, a.y); r.u[1] = pk2h(a.z, a.w);
    r.u[2] = pk2h(b.x, b.y); r.u[3] = pk2h(b.z, b.w);
    return r.s;
}

// ---------------- prep: W cast (blocks 0..639) + x cast (blocks 640..3199) ----------------
__global__ __launch_bounds__(256) void prep_all(const float* __restrict__ Wi,
                                                const float* __restrict__ Wj,
                                                const float* __restrict__ x,
                                                u16* __restrict__ Wb,
                                                u16* __restrict__ xb) {
    int bx = blockIdx.x;
    if (bx < 640) {
        int idx = bx * 256 + threadIdx.x;            // 0..163839
        float v = (idx < 81920) ? Wi[idx] : Wj[idx - 81920];
        Wb[idx] = f2bf(v);
    } else {
        int t = (bx - 640) * 256 + threadIdx.x;      // 0..655359
        #pragma unroll
        for (int i = 0; i < 4; ++i) {
            size_t g = (size_t)i * 655360 + t;       // group of 8 floats
            float4 a = *reinterpret_cast<const float4*>(x + g * 8);
            float4 b = *reinterpret_cast<const float4*>(x + g * 8 + 4);
            *reinterpret_cast<short8*>(xb + g * 8) = pack8(a, b);
        }
    }
}

// ---------------- kernel 1: gated features + norm^2 partials (bf16 A) ----------------
// Grid 512 (exactly 2 blocks/CU, ONE residency round). Block = 2 m-tiles of 256 rows x
// 128 cols (2 mats x 64 h); B full-K LDS-resident across both tiles (one prologue, one
// barrier). Wave = 32 rows x 128 cols (r6 structure), A dist-3 ring-4 (32 VGPR),
// acc 64 AGPR -> 4 waves/SIMD with no spill.
__global__ __launch_bounds__(512, 4) void gemm_gate_pre(
    const u16* __restrict__ xbg, const u16* __restrict__ Wb,
    const float* __restrict__ bi, const float* __restrict__ bj,
    u16* __restrict__ xa, float* __restrict__ normsq_p)
{
    __shared__ u16 lB[5 * 8192];      // [kt][row 0..127][swizzled k-slot*8], 81920 B

    const int bx   = blockIdx.x;      // 0..511
    const int xcd  = bx & 7;
    const int ht   = (bx >> 3) & 3;
    const int slot = bx >> 5;         // 0..15
    const int h0   = ht * 64;

    const int tid  = threadIdx.x;
    const int w    = tid >> 6;        // 0..7
    const int lane = tid & 63;
    const int quad = lane >> 4;
    const int l15  = lane & 15;

    // ---- one-time B load: 5 kt x 2 issues per wave ----
    {
        const int rsub = lane >> 3;                 // 0..7
        const int kg   = (lane & 7) ^ rsub;         // XOR swizzle
        #pragma unroll
        for (int kt = 0; kt < 5; ++kt) {
            #pragma unroll
            for (int j = 0; j < 2; ++j) {
                int sl  = w * 2 + j;                // 0..15
                int row = sl * 8 + rsub;            // 0..127
                int mat = row >> 6, hl = row & 63;
                const u16* gsrc = Wb + mat * 81920 + (size_t)(h0 + hl) * FF + kt * 64 + kg * 8;
                u16* ldst = &lB[kt * 8192 + sl * 512];
                __builtin_amdgcn_global_load_lds(
                    (const __attribute__((address_space(1))) void*)gsrc,
                    (__attribute__((address_space(3))) void*)ldst, 16, 0, 0);
            }
        }
    }

    f32x4  acc[8][2];                 // [col/16][mt]
    short8 af[4][2];                  // ring-4, dist-3

    #pragma unroll
    for (int mi = 0; mi < 2; ++mi) {
        const int mb    = xcd + (slot * 2 + mi) * 8;   // 0..255; 4 ht-blocks share XCD
        const int m0    = mb * 256;
        const int b_idx = m0 >> 13;
        const int n0    = m0 & 8191;

        const u16* xr0 = xbg + (size_t)(m0 + w * 32 + l15) * FF + quad * 8;
        const u16* xr1 = xr0 + 16 * FF;

        #pragma unroll
        for (int a = 0; a < 8; ++a)
            #pragma unroll
            for (int m = 0; m < 2; ++m) acc[a][m] = (f32x4){0.f, 0.f, 0.f, 0.f};

        #pragma unroll
        for (int s = 0; s < 3; ++s) {
            af[s][0] = *reinterpret_cast<const short8*>(xr0 + s * 32);
            af[s][1] = *reinterpret_cast<const short8*>(xr1 + s * 32);
        }

        if (mi == 0) __syncthreads();  // B resident (only needed once)

        #pragma unroll
        for (int ks = 0; ks < 10; ++ks) {
            const int kt  = ks >> 1, kk = ks & 1;
            const int cur = ks & 3;
            if (ks < 7) {
                const int nx = (ks + 3) & 3;
                af[nx][0] = *reinterpret_cast<const short8*>(xr0 + (ks + 3) * 32);
                af[nx][1] = *reinterpret_cast<const short8*>(xr1 + (ks + 3) * 32);
            }
            #pragma unroll
            for (int mn = 0; mn < 8; ++mn) {
                int c = mn * 16 + l15;
                short8 bv = *reinterpret_cast<const short8*>(
                    &lB[kt * 8192 + c * 64 + (((kk * 4 + quad) ^ (c & 7)) << 3)]);
                acc[mn][0] = __builtin_amdgcn_mfma_f32_16x16x32_bf16(af[cur][0], bv, acc[mn][0], 0, 0, 0);
                acc[mn][1] = __builtin_amdgcn_mfma_f32_16x16x32_bf16(af[cur][1], bv, acc[mn][1], 0, 0, 0);
            }
        }

        // ---- epilogue: gate, store xa [b][h][n], norm^2 partials (4 slots, no atomics) ----
        float s0[2][4];
        #pragma unroll
        for (int mt = 0; mt < 2; ++mt)
            #pragma unroll
            for (int r = 0; r < 4; ++r) s0[mt][r] = 0.f;

        #pragma unroll
        for (int hq = 0; hq < 4; ++hq) {
            int h = h0 + hq * 16 + l15;
            float bi_v = bi[h], bj_v = bj[h];
            #pragma unroll
            for (int mt = 0; mt < 2; ++mt) {
                float xall[4];
                #pragma unroll
                for (int r = 0; r < 4; ++r) {
                    float yi = acc[hq][mt][r] + bi_v;
                    float yj = acc[hq + 4][mt][r] + bj_v;
                    float sg = 1.f / (1.f + __expf(-yi));
                    float e2 = __expf(-2.f * yj);
                    float th = (1.f - e2) / (1.f + e2);
                    float xv = sg * th;
                    xall[r] = xv;
                    s0[mt][r] += xv * xv;
                }
                uint2 pk;
                pk.x = pk2h(xall[0], xall[1]);
                pk.y = pk2h(xall[2], xall[3]);
                size_t o = (size_t)b_idx * ((size_t)HH * NN) + (size_t)h * NN
                         + (size_t)(n0 + w * 32 + mt * 16 + quad * 4);
                *reinterpret_cast<uint2*>(&xa[o]) = pk;
            }
        }
        #pragma unroll
        for (int m = 1; m <= 8; m <<= 1) {
            #pragma unroll
            for (int mt = 0; mt < 2; ++mt)
                #pragma unroll
                for (int r = 0; r < 4; ++r)
                    s0[mt][r] += __shfl_xor(s0[mt][r], m, 64);
        }
        if (l15 == 0) {
            #pragma unroll
            for (int mt = 0; mt < 2; ++mt)
                #pragma unroll
                for (int r = 0; r < 4; ++r)
                    normsq_p[ht * NROWS + m0 + w * 32 + mt * 16 + quad * 4 + r] = s0[mt][r];
        }
    }
}

// ---------------- fallback (no xb space): fp32-A version, 4 partial slots ----------------
__global__ __launch_bounds__(512, 4) void gemm_gate_f32(
    const float* __restrict__ x, const u16* __restrict__ Wb,
    const float* __restrict__ bi, const float* __restrict__ bj,
    u16* __restrict__ xa, float* __restrict__ normsq_p)
{
    __shared__ u16 lB[5 * 8192];

    const int bx   = blockIdx.x;
    const int xcd  = bx & 7;
    const int ht   = (bx >> 3) & 3;
    const int slot = bx >> 5;
    const int mb   = xcd + slot * 8;
    const int m0   = mb * 256;
    const int h0   = ht * 64;
    const int b_idx = m0 >> 13;
    const int n0    = m0 & 8191;

    const int tid  = threadIdx.x;
    const int w    = tid >> 6;
    const int lane = tid & 63;
    const int quad = lane >> 4;
    const int l15  = lane & 15;

    {
        const int rsub = lane >> 3;
        const int kg   = (lane & 7) ^ rsub;
        #pragma unroll
        for (int kt = 0; kt < 5; ++kt) {
            #pragma unroll
            for (int j = 0; j < 2; ++j) {
                int sl  = w * 2 + j;
                int row = sl * 8 + rsub;
                int mat = row >> 6, hl = row & 63;
                const u16* gsrc = Wb + mat * 81920 + (size_t)(h0 + hl) * FF + kt * 64 + kg * 8;
                u16* ldst = &lB[kt * 8192 + sl * 512];
                __builtin_amdgcn_global_load_lds(
                    (const __attribute__((address_space(1))) void*)gsrc,
                    (__attribute__((address_space(3))) void*)ldst, 16, 0, 0);
            }
        }
    }

    const float* xb = x + (size_t)(m0 + w * 32 + l15) * FF + quad * 8;

    f32x4 acc[8][2];
    #pragma unroll
    for (int a = 0; a < 8; ++a)
        #pragma unroll
        for (int m = 0; m < 2; ++m) acc[a][m] = (f32x4){0.f, 0.f, 0.f, 0.f};

    float4 pre[3][2][2];
    #pragma unroll
    for (int s = 0; s < 2; ++s)
        #pragma unroll
        for (int mt = 0; mt < 2; ++mt) {
            pre[s][mt][0] = *reinterpret_cast<const float4*>(xb + mt * 16 * FF + s * 32);
            pre[s][mt][1] = *reinterpret_cast<const float4*>(xb + mt * 16 * FF + s * 32 + 4);
        }

    __syncthreads();

    #pragma unroll
    for (int ks = 0; ks < 10; ++ks) {
        const int kt  = ks >> 1, kk = ks & 1;
        const int cur = ks % 3;
        if (ks < 8) {
            const int nx = (ks + 2) % 3;
            const int f  = (ks + 2) * 32;
            #pragma unroll
            for (int mt = 0; mt < 2; ++mt) {
                pre[nx][mt][0] = *reinterpret_cast<const float4*>(xb + mt * 16 * FF + f);
                pre[nx][mt][1] = *reinterpret_cast<const float4*>(xb + mt * 16 * FF + f + 4);
            }
        }
        short8 af0 = pack8(pre[cur][0][0], pre[cur][0][1]);
        short8 af1 = pack8(pre[cur][1][0], pre[cur][1][1]);
        #pragma unroll
        for (int mn = 0; mn < 8; ++mn) {
            int c = mn * 16 + l15;
            short8 bv = *reinterpret_cast<const short8*>(
                &lB[kt * 8192 + c * 64 + (((kk * 4 + quad) ^ (c & 7)) << 3)]);
            acc[mn][0] = __builtin_amdgcn_mfma_f32_16x16x32_bf16(af0, bv, acc[mn][0], 0, 0, 0);
            acc[mn][1] = __builtin_amdgcn_mfma_f32_16x16x32_bf16(af1, bv, acc[mn][1], 0, 0, 0);
        }
    }

    float s0[2][4];
    #pragma unroll
    for (int mt = 0; mt < 2; ++mt)
        #pragma unroll
        for (int r = 0; r < 4; ++r) s0[mt][r] = 0.f;

    #pragma unroll
    for (int hq = 0; hq < 4; ++hq) {
        int h = h0 + hq * 16 + l15;
        float bi_v = bi[h], bj_v = bj[h];
        #pragma unroll
        for (int mt = 0; mt < 2; ++mt) {
            float xall[4];
            #pragma unroll
            for (int r = 0; r < 4; ++r) {
                float yi = acc[hq][mt][r] + bi_v;
                float yj = acc[hq + 4][mt][r] + bj_v;
                float sg = 1.f / (1.f + __expf(-yi));
                float e2 = __expf(-2.f * yj);
                float th = (1.f - e2) / (1.f + e2);
                float xv = sg * th;
                xall[r] = xv;
                s0[mt][r] += xv * xv;
            }
            uint2 pk;
            pk.x = pk2h(xall[0], xall[1]);
            pk.y = pk2h(xall[2], xall[3]);
            size_t o = (size_t)b_idx * ((size_t)HH * NN) + (size_t)h * NN
                     + (size_t)(n0 + w * 32 + mt * 16 + quad * 4);
            *reinterpret_cast<uint2*>(&xa[o]) = pk;
        }
    }
    #pragma unroll
    for (int m = 1; m <= 8; m <<= 1) {
        #pragma unroll
        for (int mt = 0; mt < 2; ++mt)
            #pragma unroll
            for (int r = 0; r < 4; ++r)
                s0[mt][r] += __shfl_xor(s0[mt][r], m, 64);
    }
    if (l15 == 0) {
        #pragma unroll
        for (int mt = 0; mt < 2; ++mt)
            #pragma unroll
            for (int r = 0; r < 4; ++r)
                normsq_p[ht * NROWS + m0 + w * 32 + mt * 16 + quad * 4 + r] = s0[mt][r];
    }
}

// ---------------- kernel 2: masked softmax over N per (b,s) -> out1 fp32 ----------------
__global__ __launch_bounds__(1024) void softmax_k(
    const float* __restrict__ nm, const float* __restrict__ normsq_p,
    float* __restrict__ out1)
{
    __shared__ float red[16];
    int bs = blockIdx.x;                 // 0..255
    int b  = bs >> 5;
    const float* src = nm + (size_t)bs * NN;
    float* dst       = out1 + (size_t)bs * NN;
    const float* ns  = normsq_p + (size_t)b * NN;
    int tid = threadIdx.x;
    float e[8];
    float sum = 0.f;
    #pragma unroll
    for (int i = 0; i < 8; ++i) {
        int n = i * 1024 + tid;
        float nsq = ns[n] + ns[n + NROWS] + ns[n + 2 * NROWS] + ns[n + 3 * NROWS];
        float logit = src[n] * sqrtf(nsq);
        float v = (logit > 0.f) ? __expf(logit) : 0.f;
        e[i] = v;
        sum += v;
    }
    #pragma unroll
    for (int m = 1; m <= 32; m <<= 1) sum += __shfl_xor(sum, m, 64);
    int w = tid >> 6, lane = tid & 63;
    if (lane == 0) red[w] = sum;
    __syncthreads();
    float part = 0.f;
    #pragma unroll
    for (int j = 0; j < 16; ++j) part += red[j];
    float inv = (part > 0.f) ? (1.f / part) : 0.f;
    #pragma unroll
    for (int i = 0; i < 8; ++i) dst[i * 1024 + tid] = e[i] * inv;
}

// ---------------- kernel 3: pooling GEMM partials over 256-n chunks ----------------
__global__ __launch_bounds__(256) void pooled_k(
    const u16* __restrict__ xa, const float* __restrict__ wgt,
    float* __restrict__ part)
{
    __shared__ u16 lw[32 * 264];         // [s][k] stride 264 shorts
    int bx = blockIdx.x;                 // 256
    int b  = bx >> 5, c = bx & 31;
    int n0 = c * 256;
    int tid = threadIdx.x, w = tid >> 6, lane = tid & 63, quad = lane >> 4, l15 = lane & 15;

    const u16* ab = xa + (size_t)b * ((size_t)HH * NN) + n0;

    // prefetch ks=0 A-fragments before the barrier (independent of LDS)
    short8 av[2][4];
    #pragma unroll
    for (int htl = 0; htl < 4; ++htl) {
        int h = w * 64 + htl * 16 + l15;
        av[0][htl] = *reinterpret_cast<const short8*>(ab + (size_t)h * NN + quad * 8);
    }

    // stage weights fp32 -> bf16 (32 s x 256 n)
    {
        int s  = tid >> 3;
        int nb = (tid & 7) * 32;
        const float* src = wgt + (size_t)(b * SS + s) * NN + n0 + nb;
        #pragma unroll
        for (int q = 0; q < 8; ++q) {
            float4 v = *reinterpret_cast<const float4*>(src + q * 4);
            uint2 pk;
            pk.x = pk2h(v.x, v.y);
            pk.y = pk2h(v.z, v.w);
            *reinterpret_cast<uint2*>(&lw[s * 264 + nb + q * 4]) = pk;
        }
    }
    __syncthreads();

    f32x4 acc[4][2];
    #pragma unroll
    for (int a = 0; a < 4; ++a)
        #pragma unroll
        for (int s = 0; s < 2; ++s) acc[a][s] = (f32x4){0.f, 0.f, 0.f, 0.f};

    #pragma unroll
    for (int ks = 0; ks < 8; ++ks) {
        const int cur = ks & 1, nxt = cur ^ 1;
        if (ks < 7) {
            #pragma unroll
            for (int htl = 0; htl < 4; ++htl) {
                int h = w * 64 + htl * 16 + l15;
                av[nxt][htl] = *reinterpret_cast<const short8*>(
                    ab + (size_t)h * NN + (ks + 1) * 32 + quad * 8);
            }
        }
        #pragma unroll
        for (int st = 0; st < 2; ++st) {
            int s = st * 16 + l15;
            short8 bv = *reinterpret_cast<const short8*>(&lw[s * 264 + ks * 32 + quad * 8]);
            #pragma unroll
            for (int htl = 0; htl < 4; ++htl)
                acc[htl][st] = __builtin_amdgcn_mfma_f32_16x16x32_bf16(av[cur][htl], bv, acc[htl][st], 0, 0, 0);
        }
    }
    float* pb = part + (size_t)(b * NCH + c) * 8192;   // [s*256 + h]
    #pragma unroll
    for (int htl = 0; htl < 4; ++htl) {
        #pragma unroll
        for (int st = 0; st < 2; ++st) {
            int h = w * 64 + htl * 16 + quad * 4;
            int s = st * 16 + l15;
            *reinterpret_cast<f32x4*>(&pb[s * 256 + h]) = acc[htl][st];
        }
    }
}

// ---------------- kernel 4: reduce partials over 32 chunks + tanh -> out0 ----------------
__global__ __launch_bounds__(256) void reduce_tanh(const float* __restrict__ part,
                                                   float* __restrict__ out0)
{
    int gid = blockIdx.x * 256 + threadIdx.x;   // 0..65535 = b*8192 + s*256 + h
    int b = gid >> 13, r = gid & 8191;
    const float* p = part + (size_t)b * NCH * 8192 + r;
    float s = 0.f;
    #pragma unroll
    for (int c = 0; c < NCH; ++c) s += p[(size_t)c * 8192];
    out0[gid] = tanhf(s);
}

extern "C" void kernel_launch(void* const* d_in, const int* in_sizes, int n_in,
                              void* d_out, int out_size, void* d_ws, size_t ws_size,
                              hipStream_t stream) {
    const float* x  = (const float*)d_in[0];
    const float* nm = (const float*)d_in[1];
    const float* Wi = (const float*)d_in[2];
    const float* bi = (const float*)d_in[3];
    const float* Wj = (const float*)d_in[4];
    const float* bj = (const float*)d_in[5];
    float* out0 = (float*)d_out;
    float* out1 = out0 + NB * SS * HH;           // 65536

    char* ws = (char*)d_ws;
    size_t off = 0;
    u16*   Wb       = (u16*)(ws + off);   off += 327680;
    u16*   xa       = (u16*)(ws + off);   off += 33554432;
    float* normsq_p = (float*)(ws + off); off += 1048576;    // [4][65536]
    float* part     = (float*)(ws + off); off += 8388608;    // [8][32][8192]
    u16*   xb       = (u16*)(ws + off);
    const size_t need_fast = off + 41943040;                 // + xb bf16 [65536][320]

    if (ws_size >= need_fast) {
        prep_all     <<<3200, 256, 0, stream>>>(Wi, Wj, x, Wb, xb);
        gemm_gate_pre<<<512,  512, 0, stream>>>(xb, Wb, bi, bj, xa, normsq_p);
    } else {
        prep_all     <<<640,  256, 0, stream>>>(Wi, Wj, x, Wb, xb);
        gemm_gate_f32<<<1024, 512, 0, stream>>>(x, Wb, bi, bj, xa, normsq_p);
    }
    softmax_k  <<<256, 1024, 0, stream>>>(nm, normsq_p, out1);
    pooled_k   <<<256,  256, 0, stream>>>(xa, out1, part);
    reduce_tanh<<<256,  256, 0, stream>>>(part, out0);
}